// Round 19
// baseline (84.339 us; speedup 1.0000x reference)
//
#include <hip/hip_runtime.h>

#define N_NODES 50000
#define N_EDGES 800000
#define D 64
#define NBUCK 782            // ceil(50000/64) buckets of 64 dst nodes
#define NBUCK_PAD 800
#define BINBLK 256           // bin blocks (1 per CU), single pass
#define EPB 3125             // edges per bin block (256*3125 = 800000)
#define ECHUNK 13            // ceil(3125/256)
#define SLOTS 16             // fixed slots per (block,bucket); Poisson(4) tail ~1e-6
#define CAP 1536             // stage/csr capacity per bucket (mean 1024 + 16 sigma)
#define OVFCAP 4096
#define FIXSCALE 4194304.0f  // 2^22 fixed-point for weighted degree

// ---------------- helpers ----------------

__device__ inline unsigned short f2bf(float f) {
    unsigned u = __float_as_uint(f);
    unsigned r = (u + 0x7FFFu + ((u >> 16) & 1u)) >> 16;   // RNE
    return (unsigned short)r;
}
__device__ inline float bf2f(unsigned short h) {
    return __uint_as_float(((unsigned)h) << 16);
}
__device__ inline int wave_incl_scan(int v, int lane) {
#pragma unroll
    for (int off = 1; off < 64; off <<= 1) {
        int n = __shfl_up(v, off, 64);
        if (lane >= off) v += n;
    }
    return v;
}

// ---------------- kernels ----------------

// Fused: blocks [0,BINBLK) bin edges in a SINGLE pass into fixed per-(block,
// bucket) slot regions (LDS cursors only — no global reserve, no count pass);
// blocks [BINBLK,..) compute hb = bf16(x @ W).
union ShU {
    int lh[NBUCK];                                   // bin: 3.1 KB
    struct { float Ws[D][D]; float Xs[4][D]; } gm;   // 17.4 KB
};
__global__ __launch_bounds__(256) void k_bin_gemm(
        const int* __restrict__ src, const int* __restrict__ dst,
        const float* __restrict__ ew,
        unsigned long long* __restrict__ binned,
        unsigned char* __restrict__ cnt8,
        unsigned long long* __restrict__ ovf, int* __restrict__ ovfcnt,
        const float* __restrict__ x, const float* __restrict__ W,
        unsigned short* __restrict__ hb) {
    __shared__ ShU sh;
    int t = threadIdx.x;
    int bid = blockIdx.x;
    if (bid < BINBLK) {
        int* lh = sh.lh;
        for (int i = t; i < NBUCK; i += 256) lh[i] = 0;
        __syncthreads();
        int base = bid * EPB;
#pragma unroll
        for (int i = 0; i < ECHUNK; ++i) {          // single pass: rank + store
            int k = i * 256 + t;
            if (k < EPB) {
                int e = base + k;
                int d = dst[e];
                unsigned long long p =
                    ((unsigned long long)__float_as_uint(ew[e]) << 32)
                  | ((unsigned)src[e] << 16) | (unsigned)d;
                int bkt = d >> 6;
                int rank = atomicAdd(&lh[bkt], 1);
                if (rank < SLOTS)
                    binned[((size_t)bkt * BINBLK + bid) * SLOTS + rank] = p;
                else
                    ovf[atomicAdd(ovfcnt, 1) & (OVFCAP - 1)] = p;
            }
        }
        __syncthreads();
        for (int i = t; i < NBUCK; i += 256)
            cnt8[(size_t)bid * NBUCK_PAD + i] = (unsigned char)min(lh[i], SLOTS);
    } else {
        float (*Ws)[D] = sh.gm.Ws;
        float (*Xs)[D] = sh.gm.Xs;
        for (int k = t; k < D * D; k += 256) Ws[k / D][k % D] = W[k];
        int base = (bid - BINBLK) * 16;
        int r = t >> 6, c = t & 63;
        for (int g = 0; g < 4; ++g) {
            int row = base + g * 4 + r;
            __syncthreads();   // covers Ws staging (g=0) and Xs reuse (g>0)
            Xs[r][c] = (row < N_NODES) ? x[(size_t)row * D + c] : 0.0f;
            __syncthreads();
            float acc = 0.0f;
#pragma unroll
            for (int k = 0; k < D; ++k) acc = fmaf(Xs[r][k], Ws[k][c], acc);
            if (row < N_NODES) hb[(size_t)row * D + c] = f2bf(acc);
        }
    }
}

// one block per bucket: gather the bucket's slot runs (+overflow) into LDS,
// counting-sort to per-node CSR (u32 bf16ew|src); weighted degree -> dinv;
// rc = (cnt<<12)|excl
__global__ void k_sortbucket(const unsigned long long* __restrict__ binned,
                             const unsigned char* __restrict__ cnt8,
                             const unsigned long long* __restrict__ ovf,
                             const int* __restrict__ ovfcnt,
                             unsigned* __restrict__ csr,
                             unsigned* __restrict__ rc,
                             float* __restrict__ dinv) {
    __shared__ unsigned long long stage[CAP];   // 12 KB
    __shared__ unsigned long long cw[64];       // (cnt<<40) | fix22 wsum
    __shared__ int off2[64];
    __shared__ int wsum4[4];
    __shared__ int lenSh;
    int t = threadIdx.x, lane = t & 63, w = t >> 6;
    if (t < 64) cw[t] = 0ULL;
    __syncthreads();
    int b = blockIdx.x;
    // gather: thread t owns bin-block t's run for this bucket
    int c = (int)cnt8[(size_t)t * NBUCK_PAD + b];
    int inc = wave_incl_scan(c, lane);
    if (lane == 63) wsum4[w] = inc;
    __syncthreads();
    int woff = 0;
#pragma unroll
    for (int q = 0; q < 4; ++q) woff += (q < w) ? wsum4[q] : 0;
    int off = inc - c + woff;                    // exclusive offset
    if (t == 255) lenSh = off + c;               // total
    __syncthreads();
    {
        size_t sbase = ((size_t)b * BINBLK + t) * SLOTS;
        for (int j = 0; j < c; ++j) {
            int pos = off + j;
            if (pos < CAP) stage[pos] = binned[sbase + j];
        }
    }
    __syncthreads();
    {   // overflow drain (rare)
        int novf = min(*ovfcnt, OVFCAP);
        for (int i = t; i < novf; i += 256) {
            unsigned long long p = ovf[i];
            if ((int)((p & 0xffffu) >> 6) == b) {
                int pos = atomicAdd(&lenSh, 1);
                if (pos < CAP) stage[pos] = p;
            }
        }
    }
    __syncthreads();
    int len = min(lenSh, CAP);
    for (int k = t; k < len; k += 256) {
        unsigned long long p = stage[k];
        int dl = (int)(p & 63);
        float wg = __uint_as_float((unsigned)(p >> 32));
        atomicAdd(&cw[dl], (1ULL << 40) | (unsigned long long)__float2uint_rn(wg * FIXSCALE));
    }
    __syncthreads();
    if (t < 64) {
        int cc = (int)(cw[t] >> 40);
        float wfix = (float)(cw[t] & ((1ULL << 40) - 1ULL));
        int inc2 = wave_incl_scan(cc, t);
        int excl = inc2 - cc;
        off2[t] = excl;
        int node = b * 64 + t;
        if (node < N_NODES) {
            rc[node] = ((unsigned)cc << 12) | (unsigned)excl;
            dinv[node] = rsqrtf(1.0f + wfix * (1.0f / FIXSCALE));
        }
    }
    __syncthreads();
    size_t beg = (size_t)b * CAP;
    for (int k = t; k < len; k += 256) {
        unsigned long long p = stage[k];
        int dl = (int)(p & 63);
        int r = atomicAdd(&off2[dl], 1);
        unsigned short ewb = f2bf(__uint_as_float((unsigned)(p >> 32)));
        csr[beg + r] = ((unsigned)ewb << 16) | (unsigned)((p >> 16) & 0xffffu);
    }
}

// one wave per node, two 32-lane halves processing alternate edges of each
// pair — control flow is WAVE-UNIFORM.
__global__ void k_aggregate(const unsigned short* __restrict__ hb,
                            const float* __restrict__ dinv,
                            const unsigned* __restrict__ rc,
                            const unsigned* __restrict__ csr,
                            const float* __restrict__ bias,
                            float* __restrict__ out) {
    int node = blockIdx.x * 4 + (threadIdx.x >> 6);
    int lane = threadIdx.x & 63;
    if (node >= N_NODES) return;
    int half = lane >> 5;
    int cl = lane & 31;          // column pair: cols 2cl, 2cl+1
    float di = dinv[node];
    unsigned r = rc[node];
    int cnt = (int)(r >> 12);
    size_t beg = (size_t)(node >> 6) * CAP + (r & 0xFFFu);
    float a0 = 0.0f, a1 = 0.0f, p0 = 0.0f, p1 = 0.0f;
    {   // self-loop term, counted once (half 0 lanes)
        unsigned hd = *(const unsigned*)(hb + (size_t)node * D + 2 * cl);
        float m = (half == 0) ? di : 0.0f;
        a0 = m * bf2f((unsigned short)hd);
        a1 = m * bf2f((unsigned short)(hd >> 16));
    }
    for (int b0 = 0; b0 < cnt; b0 += 64) {
        int n = min(64, cnt - b0);
        int my_src = 0;
        float my_ew = 0.0f;
        if (lane < n) {
            unsigned q = csr[beg + b0 + lane];
            my_src = (int)(q & 0xffffu);
            my_ew = bf2f((unsigned short)(q >> 16)) * dinv[my_src];  // L2-resident
        }
        int jp = 0;
        for (; jp + 3 < n; jp += 4) {        // uniform: pairs (jp, jp+1), (jp+2, jp+3)
            int iA = jp + half, iB = jp + 2 + half;
            int sA = __shfl(my_src, iA, 64);
            float eA = __shfl(my_ew, iA, 64);
            int sB = __shfl(my_src, iB, 64);
            float eB = __shfl(my_ew, iB, 64);
            unsigned hA = *(const unsigned*)(hb + (size_t)sA * D + 2 * cl);
            unsigned hB = *(const unsigned*)(hb + (size_t)sB * D + 2 * cl);
            a0 = fmaf(bf2f((unsigned short)hA), eA, a0);
            a1 = fmaf(bf2f((unsigned short)(hA >> 16)), eA, a1);
            p0 = fmaf(bf2f((unsigned short)hB), eB, p0);
            p1 = fmaf(bf2f((unsigned short)(hB >> 16)), eB, p1);
        }
        for (; jp + 1 < n; jp += 2) {        // uniform: one pair
            int iA = jp + half;
            int sA = __shfl(my_src, iA, 64);
            float eA = __shfl(my_ew, iA, 64);
            unsigned hA = *(const unsigned*)(hb + (size_t)sA * D + 2 * cl);
            a0 = fmaf(bf2f((unsigned short)hA), eA, a0);
            a1 = fmaf(bf2f((unsigned short)(hA >> 16)), eA, a1);
        }
        if (jp < n) {                        // lone last edge: uniform shfl, half0 FMA
            int sA = __shfl(my_src, jp, 64);
            float eA = __shfl(my_ew, jp, 64);
            unsigned hA = *(const unsigned*)(hb + (size_t)sA * D + 2 * cl);
            float m = (half == 0) ? eA : 0.0f;
            a0 = fmaf(bf2f((unsigned short)hA), m, a0);
            a1 = fmaf(bf2f((unsigned short)(hA >> 16)), m, a1);
        }
    }
    a0 += p0; a1 += p1;
    a0 += __shfl_xor(a0, 32, 64);            // combine halves
    a1 += __shfl_xor(a1, 32, 64);
    if (half == 0) {
        float v0 = fmaf(di, a0, bias[2 * cl]);
        float v1 = fmaf(di, a1, bias[2 * cl + 1]);
        float2 o;
        o.x = fmaxf(v0, 0.0f);
        o.y = fmaxf(v1, 0.0f);
        *(float2*)(out + (size_t)node * D + 2 * cl) = o;
    }
}

// ---------------- launch ----------------

extern "C" void kernel_launch(void* const* d_in, const int* in_sizes, int n_in,
                              void* d_out, int out_size, void* d_ws, size_t ws_size,
                              hipStream_t stream) {
    const float* x  = (const float*)d_in[0];
    const int*   ei = (const int*)d_in[1];    // [2, E] row-major, int32
    const float* ew = (const float*)d_in[2];
    const float* W  = (const float*)d_in[3];
    const float* b  = (const float*)d_in[4];
    float* out = (float*)d_out;

    const int* src = ei;
    const int* dst = ei + N_EDGES;

    // workspace layout (8B-aligned first)
    unsigned long long* binned = (unsigned long long*)d_ws;          // NBUCK*256*16 u64 (25.6MB)
    unsigned long long* ovf = binned + (size_t)NBUCK * BINBLK * SLOTS;  // OVFCAP u64
    unsigned* csr      = (unsigned*)(ovf + OVFCAP);                  // NBUCK*CAP u32 (4.8MB)
    int*   ovfcnt      = (int*)(csr + (size_t)NBUCK * CAP);          // 16
    unsigned* rc       = (unsigned*)(ovfcnt + 16);                   // 50048
    float* dinv        = (float*)(rc + 50048);                       // 50048
    unsigned char* cnt8 = (unsigned char*)(dinv + 50048);            // 256*800 (200KB)
    unsigned short* hb = (unsigned short*)(cnt8 + (size_t)BINBLK * NBUCK_PAD);  // N*D bf16

    dim3 blk(256);
    (void)hipMemsetAsync(ovfcnt, 0, sizeof(int), stream);
    int gemmblk = (N_NODES + 15) / 16;
    k_bin_gemm<<<BINBLK + gemmblk, blk, 0, stream>>>(src, dst, ew, binned, cnt8,
                                                     ovf, ovfcnt, x, W, hb);
    k_sortbucket<<<NBUCK, blk, 0, stream>>>(binned, cnt8, ovf, ovfcnt, csr, rc, dinv);
    k_aggregate<<<(N_NODES + 3) / 4, blk, 0, stream>>>(hb, dinv, rc, csr, b, out);
}